// Round 3
// baseline (4525.816 us; speedup 1.0000x reference)
//
#include <hip/hip_runtime.h>
#include <hip/hip_bf16.h>

// Problem constants
#define BN 262144
#define DD 64
#define KC 1024

// ---- Output layout (FLOAT32 elements), reference tuple return order ----
// codes [B] | quantized [B*D] | residuals [B*D] | loss [1] | new_emb [K*D]
// | new_cluster_size [K] | new_embed_sum [K*D]
// Round-2 evidence: d_out is an fp32 buffer (absmax 1026.27 = 1024-ref +
// 2.27 from bf16-pair misreads proved the harness decodes fp32).
#define OUT_Q_OFF   (BN)
#define OUT_R_OFF   (BN + BN * DD)
#define OUT_LOSS    (BN + 2 * BN * DD)

// ---- Scratch overlay (fp32) inside the quantized output slab (64 MB).
// Dead until vq_pass2 runs; vq_fin consumes it first. d_ws unused.
#define S_COUNTS   0        // KC floats
#define S_ESUM     1024     // KC*DD floats
#define S_LOSS     66560    // 1 float
#define S_ENORM    66564    // KC floats  (fp32 |e_k|^2)
#define S_ENORM64  67588    // KC doubles (fp64 |e_k|^2), 8B-aligned (67588*4 % 8 == 0)
#define S_ZERO_N   66561    // counts + esum + loss

#define ARGMIN_MARGIN 1e-3f  // >> 2x worst-case fp32 distance error (~2.5e-4)

// Zero accumulators + precompute |e_k|^2 in fp32 and fp64
__global__ __launch_bounds__(256) void vq_init(const float* __restrict__ emb,
                                               float* __restrict__ S) {
    int i = blockIdx.x * 256 + threadIdx.x;
    if (i < S_ZERO_N) S[i] = 0.0f;
    if (i < KC) {
        const float4* e4 = (const float4*)(emb + (size_t)i * DD);
        float a0 = 0.f, a1 = 0.f, a2 = 0.f, a3 = 0.f;
        double b0 = 0., b1 = 0., b2 = 0., b3 = 0.;
#pragma unroll
        for (int j = 0; j < 16; ++j) {
            float4 e = e4[j];
            a0 = fmaf(e.x, e.x, a0); a1 = fmaf(e.y, e.y, a1);
            a2 = fmaf(e.z, e.z, a2); a3 = fmaf(e.w, e.w, a3);
            b0 = fma((double)e.x, (double)e.x, b0);
            b1 = fma((double)e.y, (double)e.y, b1);
            b2 = fma((double)e.z, (double)e.z, b2);
            b3 = fma((double)e.w, (double)e.w, b3);
        }
        S[S_ENORM + i] = (a0 + a1) + (a2 + a3);
        ((double*)(S + S_ENORM64))[i] = (b0 + b1) + (b2 + b3);
    }
}

// Pass 1: per-thread row. fp32 top-2 scan; fp64 re-resolve when the top-2 gap
// is inside fp32 noise (argmin then matches any summation-order variant).
// Writes codes as fp32; accumulates counts/esum/loss into scratch.
__global__ __launch_bounds__(256) void vq_pass1(
    const float* __restrict__ x,
    const float* __restrict__ emb,
    float* S,
    float* __restrict__ out_codes) {
    const int row = blockIdx.x * 256 + threadIdx.x;

    const float4* xr = (const float4*)(x + (size_t)row * DD);
    float4 xq[16];
#pragma unroll
    for (int i = 0; i < 16; ++i) xq[i] = xr[i];

    const float* enorm = S + S_ENORM;
    float best1 = 3.4e38f, best2 = 3.4e38f;
    int k1 = 0;
    for (int k = 0; k < KC; ++k) {
        const float4* e4 = (const float4*)(emb + (size_t)k * DD);
        float a0 = 0.f, a1 = 0.f, a2 = 0.f, a3 = 0.f;
#pragma unroll
        for (int i = 0; i < 16; ++i) {
            float4 e = e4[i];
            a0 = fmaf(xq[i].x, e.x, a0); a1 = fmaf(xq[i].y, e.y, a1);
            a2 = fmaf(xq[i].z, e.z, a2); a3 = fmaf(xq[i].w, e.w, a3);
        }
        float dist = enorm[k] - 2.0f * ((a0 + a1) + (a2 + a3));
        bool c1 = dist < best1;                       // strict <: keeps FIRST min
        bool c2 = dist < best2;
        best2 = c1 ? best1 : (c2 ? dist : best2);
        best1 = c1 ? dist : best1;
        k1    = c1 ? k : k1;
    }

    int bestk = k1;
    if (best2 - best1 < ARGMIN_MARGIN) {
        // Rare slow path: fp64-resolve all candidates within the margin.
        const double* enorm64 = (const double*)(S + S_ENORM64);
        const float limit = best1 + ARGMIN_MARGIN;
        double bd = 1e300;
        int bk = k1;
        for (int k = 0; k < KC; ++k) {
            const float4* e4 = (const float4*)(emb + (size_t)k * DD);
            float a0 = 0.f, a1 = 0.f, a2 = 0.f, a3 = 0.f;
#pragma unroll
            for (int i = 0; i < 16; ++i) {
                float4 e = e4[i];
                a0 = fmaf(xq[i].x, e.x, a0); a1 = fmaf(xq[i].y, e.y, a1);
                a2 = fmaf(xq[i].z, e.z, a2); a3 = fmaf(xq[i].w, e.w, a3);
            }
            float dist = enorm[k] - 2.0f * ((a0 + a1) + (a2 + a3));
            if (dist < limit) {
                double c0 = 0., c1d = 0., c2d = 0., c3 = 0.;
#pragma unroll
                for (int i = 0; i < 16; ++i) {
                    float4 e = e4[i];
                    c0 = fma((double)xq[i].x, (double)e.x, c0);
                    c1d = fma((double)xq[i].y, (double)e.y, c1d);
                    c2d = fma((double)xq[i].z, (double)e.z, c2d);
                    c3 = fma((double)xq[i].w, (double)e.w, c3);
                }
                double d64 = enorm64[k] - 2.0 * ((c0 + c1d) + (c2d + c3));
                if (d64 < bd) { bd = d64; bk = k; }   // strict <: first index
            }
        }
        bestk = bk;
    }

    out_codes[row] = (float)bestk;

    // Stats: loss partial + counts + esum scatter
    const float4* eb = (const float4*)(emb + (size_t)bestk * DD);
    float lsum = 0.f;
#pragma unroll
    for (int i = 0; i < 16; ++i) {
        float4 e = eb[i];
        float4 xv = xq[i];
        float rx = xv.x - e.x, ry = xv.y - e.y, rz = xv.z - e.z, rw = xv.w - e.w;
        lsum += rx * rx + ry * ry + rz * rz + rw * rw;
        atomicAdd(&S[S_ESUM + bestk * DD + 4 * i + 0], xv.x);
        atomicAdd(&S[S_ESUM + bestk * DD + 4 * i + 1], xv.y);
        atomicAdd(&S[S_ESUM + bestk * DD + 4 * i + 2], xv.z);
        atomicAdd(&S[S_ESUM + bestk * DD + 4 * i + 3], xv.w);
    }
    atomicAdd(&S[S_COUNTS + bestk], 1.0f);

#pragma unroll
    for (int off = 32; off > 0; off >>= 1) lsum += __shfl_down(lsum, off, 64);
    if ((threadIdx.x & 63) == 0) atomicAdd(&S[S_LOSS], lsum);
}

// Finalize EMA outputs + loss (consumes scratch; must run BEFORE vq_pass2)
__global__ __launch_bounds__(256) void vq_fin(
    const float* __restrict__ S,
    const float* __restrict__ ema_cs,
    const float* __restrict__ ema_es,
    float* __restrict__ out_loss,
    float* __restrict__ out_ne,
    float* __restrict__ out_ncs,
    float* __restrict__ out_nes) {
    int i = blockIdx.x * 256 + threadIdx.x;  // 0..K*D-1
    int k = i >> 6;
    float cs = 0.99f * ema_cs[k] + 0.01f * S[S_COUNTS + k];
    float es = 0.99f * ema_es[i] + 0.01f * S[S_ESUM + i];
    float n = fmaxf(cs, 1e-5f);
    out_nes[i] = es;
    out_ne[i] = es / n;
    if ((i & 63) == 0) out_ncs[k] = cs;
    if (i == 0) out_loss[0] = S[S_LOSS] * 1.25f * (1.0f / 16777216.0f);
}

// Pass 2: write quantized/residuals as fp32 (overwrites the dead scratch).
__global__ __launch_bounds__(256) void vq_pass2(
    const float* __restrict__ x,
    const float* __restrict__ emb,
    const float* __restrict__ out_codes,
    float4* __restrict__ out_q,
    float4* __restrict__ out_r) {
    const int row = blockIdx.x * 256 + threadIdx.x;
    const int code = (int)out_codes[row];

    const float4* xr = (const float4*)(x + (size_t)row * DD);
    const float4* eb = (const float4*)(emb + (size_t)code * DD);
#pragma unroll
    for (int i = 0; i < 16; ++i) {
        float4 xv = xr[i];
        float4 e = eb[i];
        // quantized = x + (e - x); residual = x - e   (fp32, like the ref)
        float4 q, r;
        q.x = xv.x + (e.x - xv.x); q.y = xv.y + (e.y - xv.y);
        q.z = xv.z + (e.z - xv.z); q.w = xv.w + (e.w - xv.w);
        r.x = xv.x - e.x; r.y = xv.y - e.y; r.z = xv.z - e.z; r.w = xv.w - e.w;
        out_q[(size_t)row * 16 + i] = q;
        out_r[(size_t)row * 16 + i] = r;
    }
}

extern "C" void kernel_launch(void* const* d_in, const int* in_sizes, int n_in,
                              void* d_out, int out_size, void* d_ws, size_t ws_size,
                              hipStream_t stream) {
    const float* x      = (const float*)d_in[0];
    const float* emb    = (const float*)d_in[1];
    const float* ema_cs = (const float*)d_in[2];
    const float* ema_es = (const float*)d_in[3];

    float* out = (float*)d_out;
    float*  out_codes = out;
    float4* out_q     = (float4*)(out + OUT_Q_OFF);
    float4* out_r     = (float4*)(out + OUT_R_OFF);
    float*  out_loss  = out + OUT_LOSS;
    float*  out_ne    = out_loss + 1;
    float*  out_ncs   = out_ne + KC * DD;
    float*  out_nes   = out_ncs + KC;

    // Scratch overlay in the quantized-output slab (1 MB-aligned). d_ws unused.
    float* S = out + OUT_Q_OFF;

    vq_init<<<(S_ZERO_N + 255) / 256, 256, 0, stream>>>(emb, S);
    vq_pass1<<<BN / 256, 256, 0, stream>>>(x, emb, S, out_codes);
    vq_fin<<<(KC * DD) / 256, 256, 0, stream>>>(S, ema_cs, ema_es,
                                                out_loss, out_ne, out_ncs, out_nes);
    vq_pass2<<<BN / 256, 256, 0, stream>>>(x, emb, out_codes, out_q, out_r);
}

// Round 4
// 2606.008 us; speedup vs baseline: 1.7367x; 1.7367x over previous
//
#include <hip/hip_runtime.h>
#include <hip/hip_bf16.h>

// Problem constants
#define BN 262144
#define DD 64
#define KC 1024
#define HB 64            // histogram/scatter blocks
#define ROWS_PER_HB (BN / HB)   // 4096

// ---- Output layout (FLOAT32 elements), reference tuple return order ----
// codes [B] | quantized [B*D] | residuals [B*D] | loss [1] | new_emb [K*D]
// | new_cluster_size [K] | new_embed_sum [K*D]
#define OUT_Q_OFF   (BN)
#define OUT_R_OFF   (BN + BN * DD)
#define OUT_LOSS    (BN + 2 * BN * DD)

// ---- Scratch overlay (element offsets into S = out + OUT_Q_OFF, the
// quantized slab, 64 MB). Consumed by vq_reduce before vq_pass2 overwrites.
// Round-3 evidence: 16.8M device atomics ran memory-side (545 MB HBM write)
// => scatter must be privatized; d_ws still untrusted/unused.
#define S_LOSS      0                         // 1 f32
#define S_ENORM     4                         // KC f32
#define S_ENORM64   (S_ENORM + KC)            // KC f64 (2*KC f32 slots; 8B-aligned)
#define S_COUNT     (S_ENORM64 + 2 * KC)      // KC i32
#define S_OFFSET    (S_COUNT + KC)            // KC i32 (exclusive prefix)
#define S_BLOCKHIST (S_OFFSET + KC)           // HB*KC i32
#define S_BASE      (S_BLOCKHIST + HB * KC)   // HB*KC i32
#define S_PERM      (S_BASE + HB * KC)        // BN i32

#define ARGMIN_MARGIN 1e-3f  // >> 2x worst-case fp32 distance error (~2.5e-4)

// Zero loss + precompute |e_k|^2 in fp32 and fp64
__global__ __launch_bounds__(256) void vq_init(const float* __restrict__ emb,
                                               float* __restrict__ S) {
    int i = blockIdx.x * 256 + threadIdx.x;
    if (i == 0) S[S_LOSS] = 0.0f;
    if (i < KC) {
        const float4* e4 = (const float4*)(emb + (size_t)i * DD);
        float a0 = 0.f, a1 = 0.f, a2 = 0.f, a3 = 0.f;
        double b0 = 0., b1 = 0., b2 = 0., b3 = 0.;
#pragma unroll
        for (int j = 0; j < 16; ++j) {
            float4 e = e4[j];
            a0 = fmaf(e.x, e.x, a0); a1 = fmaf(e.y, e.y, a1);
            a2 = fmaf(e.z, e.z, a2); a3 = fmaf(e.w, e.w, a3);
            b0 = fma((double)e.x, (double)e.x, b0);
            b1 = fma((double)e.y, (double)e.y, b1);
            b2 = fma((double)e.z, (double)e.z, b2);
            b3 = fma((double)e.w, (double)e.w, b3);
        }
        S[S_ENORM + i] = (a0 + a1) + (a2 + a3);
        ((double*)(S + S_ENORM64))[i] = (b0 + b1) + (b2 + b3);
    }
}

// Pass 1: per-thread-row argmin (fp32 top-2 + fp64 tie-resolve), codes as
// fp32, per-wave loss atomic. NO per-element scatter atomics.
__global__ __launch_bounds__(256) void vq_pass1(
    const float* __restrict__ x,
    const float* __restrict__ emb,
    float* S,
    float* __restrict__ out_codes) {
    const int row = blockIdx.x * 256 + threadIdx.x;

    const float4* xr = (const float4*)(x + (size_t)row * DD);
    float4 xq[16];
#pragma unroll
    for (int i = 0; i < 16; ++i) xq[i] = xr[i];

    const float* enorm = S + S_ENORM;
    float best1 = 3.4e38f, best2 = 3.4e38f;
    int k1 = 0;
    for (int k = 0; k < KC; ++k) {
        const float4* e4 = (const float4*)(emb + (size_t)k * DD);
        float a0 = 0.f, a1 = 0.f, a2 = 0.f, a3 = 0.f;
#pragma unroll
        for (int i = 0; i < 16; ++i) {
            float4 e = e4[i];
            a0 = fmaf(xq[i].x, e.x, a0); a1 = fmaf(xq[i].y, e.y, a1);
            a2 = fmaf(xq[i].z, e.z, a2); a3 = fmaf(xq[i].w, e.w, a3);
        }
        float dist = enorm[k] - 2.0f * ((a0 + a1) + (a2 + a3));
        bool c1 = dist < best1;                       // strict <: keeps FIRST min
        bool c2 = dist < best2;
        best2 = c1 ? best1 : (c2 ? dist : best2);
        best1 = c1 ? dist : best1;
        k1    = c1 ? k : k1;
    }

    int bestk = k1;
    if (best2 - best1 < ARGMIN_MARGIN) {
        const double* enorm64 = (const double*)(S + S_ENORM64);
        const float limit = best1 + ARGMIN_MARGIN;
        double bd = 1e300;
        int bk = k1;
        for (int k = 0; k < KC; ++k) {
            const float4* e4 = (const float4*)(emb + (size_t)k * DD);
            float a0 = 0.f, a1 = 0.f, a2 = 0.f, a3 = 0.f;
#pragma unroll
            for (int i = 0; i < 16; ++i) {
                float4 e = e4[i];
                a0 = fmaf(xq[i].x, e.x, a0); a1 = fmaf(xq[i].y, e.y, a1);
                a2 = fmaf(xq[i].z, e.z, a2); a3 = fmaf(xq[i].w, e.w, a3);
            }
            float dist = enorm[k] - 2.0f * ((a0 + a1) + (a2 + a3));
            if (dist < limit) {
                double c0 = 0., c1d = 0., c2d = 0., c3 = 0.;
#pragma unroll
                for (int i = 0; i < 16; ++i) {
                    float4 e = e4[i];
                    c0 = fma((double)xq[i].x, (double)e.x, c0);
                    c1d = fma((double)xq[i].y, (double)e.y, c1d);
                    c2d = fma((double)xq[i].z, (double)e.z, c2d);
                    c3 = fma((double)xq[i].w, (double)e.w, c3);
                }
                double d64 = enorm64[k] - 2.0 * ((c0 + c1d) + (c2d + c3));
                if (d64 < bd) { bd = d64; bk = k; }
            }
        }
        bestk = bk;
    }

    out_codes[row] = (float)bestk;

    // Commitment-loss partial (needs best-code residual)
    const float4* eb = (const float4*)(emb + (size_t)bestk * DD);
    float lsum = 0.f;
#pragma unroll
    for (int i = 0; i < 16; ++i) {
        float4 e = eb[i];
        float4 xv = xq[i];
        float rx = xv.x - e.x, ry = xv.y - e.y, rz = xv.z - e.z, rw = xv.w - e.w;
        lsum += rx * rx + ry * ry + rz * rz + rw * rw;
    }
#pragma unroll
    for (int off = 32; off > 0; off >>= 1) lsum += __shfl_down(lsum, off, 64);
    if ((threadIdx.x & 63) == 0) atomicAdd(&S[S_LOSS], lsum);
}

// Histogram: per-block LDS hist over 4096 rows, plain-store to blockhist.
__global__ __launch_bounds__(256) void vq_hist(const float* __restrict__ codes,
                                               float* S) {
    __shared__ int lh[KC];
    const int b = blockIdx.x, t = threadIdx.x;
    int* blockhist = (int*)(S + S_BLOCKHIST);
#pragma unroll
    for (int j = 0; j < 4; ++j) lh[t + 256 * j] = 0;
    __syncthreads();
#pragma unroll
    for (int j = 0; j < 16; ++j) {
        int k = (int)codes[b * ROWS_PER_HB + j * 256 + t];
        atomicAdd(&lh[k], 1);   // LDS atomic
    }
    __syncthreads();
#pragma unroll
    for (int j = 0; j < 4; ++j) {
        int k = t + 256 * j;
        blockhist[b * KC + k] = lh[k];
    }
}

// Scan: counts = column sums; exclusive prefix over K; per-block bases.
__global__ __launch_bounds__(1024) void vq_scan(float* S) {
    __shared__ int sc[KC];
    const int k = threadIdx.x;
    int* blockhist = (int*)(S + S_BLOCKHIST);
    int* base      = (int*)(S + S_BASE);
    int* count     = (int*)(S + S_COUNT);
    int* offset    = (int*)(S + S_OFFSET);

    int s = 0;
    for (int b = 0; b < HB; ++b) {
        base[b * KC + k] = s;           // in-block running start (pre-offset)
        s += blockhist[b * KC + k];
    }
    count[k] = s;
    sc[k] = s;
    __syncthreads();
    for (int st = 1; st < KC; st <<= 1) {
        int v = (k >= st) ? sc[k - st] : 0;
        __syncthreads();
        sc[k] += v;
        __syncthreads();
    }
    int off = (k == 0) ? 0 : sc[k - 1];  // exclusive
    offset[k] = off;
    for (int b = 0; b < HB; ++b) base[b * KC + k] += off;
}

// Scatter: LDS cursors (LDS atomics only) -> perm row-index lists.
__global__ __launch_bounds__(256) void vq_scatter(const float* __restrict__ codes,
                                                  float* S) {
    __shared__ int cur[KC];
    const int b = blockIdx.x, t = threadIdx.x;
    int* base = (int*)(S + S_BASE);
    int* perm = (int*)(S + S_PERM);
#pragma unroll
    for (int j = 0; j < 4; ++j) {
        int k = t + 256 * j;
        cur[k] = base[b * KC + k];
    }
    __syncthreads();
#pragma unroll
    for (int j = 0; j < 16; ++j) {
        int row = b * ROWS_PER_HB + j * 256 + t;
        int k = (int)codes[row];
        int slot = atomicAdd(&cur[k], 1);   // LDS atomic
        perm[slot] = row;
    }
}

// Reduce: one block per code; gather rows, cross-wave LDS reduce, fused EMA
// epilogue writes new_embed_sum / new_embeddings / new_cluster_size (+loss).
__global__ __launch_bounds__(256) void vq_reduce(
    const float* __restrict__ x,
    const float* __restrict__ S,
    const float* __restrict__ ema_cs,
    const float* __restrict__ ema_es,
    float* __restrict__ out_loss,
    float* __restrict__ out_ne,
    float* __restrict__ out_ncs,
    float* __restrict__ out_nes) {
    __shared__ float part[4][DD];
    const int k = blockIdx.x;
    const int t = threadIdx.x, d = t & 63, w = t >> 6;
    const int* count  = (const int*)(S + S_COUNT);
    const int* offset = (const int*)(S + S_OFFSET);
    const int* perm   = (const int*)(S + S_PERM);

    const int n = count[k], start = offset[k];
    float acc = 0.f;
    int i = w;
    for (; i + 4 < n; i += 8) {
        int r0 = perm[start + i];
        int r1 = perm[start + i + 4];
        float v0 = x[(size_t)r0 * DD + d];
        float v1 = x[(size_t)r1 * DD + d];
        acc += v0 + v1;
    }
    for (; i < n; i += 4) acc += x[(size_t)perm[start + i] * DD + d];

    part[w][d] = acc;
    __syncthreads();
    if (t < DD) {
        float es_raw = part[0][t] + part[1][t] + part[2][t] + part[3][t];
        float cs = 0.99f * ema_cs[k] + 0.01f * (float)n;
        float es = 0.99f * ema_es[(size_t)k * DD + t] + 0.01f * es_raw;
        out_nes[(size_t)k * DD + t] = es;
        out_ne[(size_t)k * DD + t] = es / fmaxf(cs, 1e-5f);
        if (t == 0) {
            out_ncs[k] = cs;
            if (k == 0) out_loss[0] = S[S_LOSS] * 1.25f * (1.0f / 16777216.0f);
        }
    }
}

// Pass 2: quantized/residuals (fp32); overwrites the dead scratch overlay.
__global__ __launch_bounds__(256) void vq_pass2(
    const float* __restrict__ x,
    const float* __restrict__ emb,
    const float* __restrict__ out_codes,
    float4* __restrict__ out_q,
    float4* __restrict__ out_r) {
    const int row = blockIdx.x * 256 + threadIdx.x;
    const int code = (int)out_codes[row];

    const float4* xr = (const float4*)(x + (size_t)row * DD);
    const float4* eb = (const float4*)(emb + (size_t)code * DD);
#pragma unroll
    for (int i = 0; i < 16; ++i) {
        float4 xv = xr[i];
        float4 e = eb[i];
        float4 q, r;
        q.x = xv.x + (e.x - xv.x); q.y = xv.y + (e.y - xv.y);
        q.z = xv.z + (e.z - xv.z); q.w = xv.w + (e.w - xv.w);
        r.x = xv.x - e.x; r.y = xv.y - e.y; r.z = xv.z - e.z; r.w = xv.w - e.w;
        out_q[(size_t)row * 16 + i] = q;
        out_r[(size_t)row * 16 + i] = r;
    }
}

extern "C" void kernel_launch(void* const* d_in, const int* in_sizes, int n_in,
                              void* d_out, int out_size, void* d_ws, size_t ws_size,
                              hipStream_t stream) {
    const float* x      = (const float*)d_in[0];
    const float* emb    = (const float*)d_in[1];
    const float* ema_cs = (const float*)d_in[2];
    const float* ema_es = (const float*)d_in[3];

    float* out = (float*)d_out;
    float*  out_codes = out;
    float4* out_q     = (float4*)(out + OUT_Q_OFF);
    float4* out_r     = (float4*)(out + OUT_R_OFF);
    float*  out_loss  = out + OUT_LOSS;
    float*  out_ne    = out_loss + 1;
    float*  out_ncs   = out_ne + KC * DD;
    float*  out_nes   = out_ncs + KC;

    float* S = out + OUT_Q_OFF;   // scratch overlay in quantized slab

    vq_init<<<(KC + 255) / 256, 256, 0, stream>>>(emb, S);
    vq_pass1<<<BN / 256, 256, 0, stream>>>(x, emb, S, out_codes);
    vq_hist<<<HB, 256, 0, stream>>>(out_codes, S);
    vq_scan<<<1, 1024, 0, stream>>>(S);
    vq_scatter<<<HB, 256, 0, stream>>>(out_codes, S);
    vq_reduce<<<KC, 256, 0, stream>>>(x, S, ema_cs, ema_es,
                                      out_loss, out_ne, out_ncs, out_nes);
    vq_pass2<<<BN / 256, 256, 0, stream>>>(x, emb, out_codes, out_q, out_r);
}